// Round 11
// baseline (231.524 us; speedup 1.0000x reference)
//
#include <hip/hip_runtime.h>
#include <hip/hip_bf16.h>

#define NN 100000
#define NE 1600000
#define NF 128
#define NH1 256
#define NH2 32
#define NC 16

#define NB 196          // row buckets (512 rows each)
#define BSH 9
#define NCHUNK 512
#define CHSZ (NE / NCHUNK)   // 3125
#define NKEY 1024            // (row_local, colseg) bins

typedef __attribute__((ext_vector_type(4))) float f32x4;
typedef __attribute__((ext_vector_type(8))) short s16x8;
typedef __attribute__((ext_vector_type(4))) short s16x4;

__device__ __forceinline__ unsigned short f2bu(float f) {
    union { float f; unsigned u; } v; v.f = f;
    unsigned r = v.u + 0x7FFFu + ((v.u >> 16) & 1u);
    return (unsigned short)(r >> 16);
}
__device__ __forceinline__ float bflo(unsigned w) { return __uint_as_float(w << 16); }
__device__ __forceinline__ float bfhi(unsigned w) { return __uint_as_float(w & 0xFFFF0000u); }

// int64-vs-int32 probe, inlined per consuming block (16 uniform loads)
__device__ __forceinline__ int detect_st(const int* arow) {
    const unsigned* a = (const unsigned*)arow;
    unsigned acc = 0;
#pragma unroll
    for (int i = 1; i < 32; i += 2) acc |= a[i];
    return acc == 0u ? 2 : 1;
}

// ---- fat0: hist (blocks 0..511) | xconv (512..1535) | prep (1536..1695) ----
__global__ __launch_bounds__(256) void fat0_k(const float* __restrict__ x, short* __restrict__ xb,
                                              const float* __restrict__ W1, const float* __restrict__ W2,
                                              short* __restrict__ w1t, short* __restrict__ w2t,
                                              const int* __restrict__ arow, int* __restrict__ histc) {
    int bid = blockIdx.x;
    if (bid < NCHUNK) {                       // per-chunk bucket histogram
        __shared__ int h[NB];
        for (int j = threadIdx.x; j < NB; j += 256) h[j] = 0;
        __syncthreads();
        int st = detect_st(arow);
        int base = bid * CHSZ;
        for (int i = base + threadIdx.x; i < base + CHSZ; i += 256)
            atomicAdd(&h[arow[(size_t)i * st] >> BSH], 1);
        __syncthreads();
        for (int j = threadIdx.x; j < NB; j += 256) histc[bid * NB + j] = h[j];
    } else if (bid < NCHUNK + 1024) {         // x -> bf16
        const int total = NN * NF / 4;
        for (int i = (bid - NCHUNK) * 256 + threadIdx.x; i < total; i += 1024 * 256) {
            f32x4 v = ((const f32x4*)x)[i];
            s16x4 o;
            for (int j = 0; j < 4; ++j) o[j] = (short)f2bu(v[j]);
            ((s16x4*)xb)[i] = o;
        }
    } else {                                  // weight transpose + bf16
        int i = (bid - NCHUNK - 1024) * 256 + threadIdx.x;
        if (i < NF * NH1) {
            int k = i / NH1, c = i % NH1;
            w1t[c * NF + k] = (short)f2bu(W1[i]);
        } else {
            int j = i - NF * NH1;
            if (j < NH1 * NH2) {
                int k = j / NH2, c = j % NH2;
                w2t[c * NH1 + k] = (short)f2bu(W2[j]);
            }
        }
    }
}

// ---- B1: per-bucket exclusive scan over chunks ----
__global__ __launch_bounds__(256) void scanb_k(const int* __restrict__ histc,
                                               int* __restrict__ cur,
                                               int* __restrict__ totals) {
    __shared__ int s[256];
    int b = blockIdx.x, t = threadIdx.x;
    int v0 = histc[(2 * t) * NB + b], v1 = histc[(2 * t + 1) * NB + b];
    int sum = v0 + v1;
    s[t] = sum; __syncthreads();
    for (int off = 1; off < 256; off <<= 1) {
        int u = (t >= off) ? s[t - off] : 0;
        __syncthreads();
        s[t] += u;
        __syncthreads();
    }
    int excl = s[t] - sum;
    cur[(2 * t) * NB + b] = excl;
    cur[(2 * t + 1) * NB + b] = excl + v0;
    if (t == 255) totals[b] = s[255];
}

// ---- C: scatter via LDS staging -> run-coalesced global writes ----
__global__ __launch_bounds__(256) void scat_k(const int* __restrict__ arow,
                                              const int* __restrict__ acol,
                                              const float* __restrict__ avals,
                                              const int* __restrict__ totals,
                                              const int* __restrict__ histc,
                                              const int* __restrict__ cur,
                                              uint2* __restrict__ recs) {
    __shared__ uint2 stage[CHSZ];     // 25000 B
    __shared__ int desti[CHSZ];       // 12500 B
    __shared__ int gb[NB];            // gbase[b] - binoff[b]
    __shared__ int bincur[NB];
    __shared__ int ss[256];
    int c = blockIdx.x, t = threadIdx.x;
    int tv = (t < NB) ? totals[t] : 0;
    ss[t] = tv; __syncthreads();
    for (int off = 1; off < 256; off <<= 1) {
        int u = (t >= off) ? ss[t - off] : 0;
        __syncthreads();
        ss[t] += u;
        __syncthreads();
    }
    int bstart = ss[t] - tv;
    if (t < NB) gb[t] = bstart + cur[c * NB + t];
    __syncthreads();
    int hv = (t < NB) ? histc[c * NB + t] : 0;
    ss[t] = hv; __syncthreads();
    for (int off = 1; off < 256; off <<= 1) {
        int u = (t >= off) ? ss[t - off] : 0;
        __syncthreads();
        ss[t] += u;
        __syncthreads();
    }
    int boff = ss[t] - hv;
    if (t < NB) { bincur[t] = boff; gb[t] -= boff; }
    __syncthreads();
    int st = detect_st(arow);
    int base = c * CHSZ;
    for (int i = base + t; i < base + CHSZ; i += 256) {
        int r   = arow[(size_t)i * st];
        int col = acol[(size_t)i * st];
        float v = avals[i];
        int b = r >> BSH;
        int p = atomicAdd(&bincur[b], 1);
        uint2 rec;
        rec.x = (unsigned)col | ((unsigned)(r & 511) << 17);
        rec.y = __float_as_uint(v);
        stage[p] = rec;
        desti[p] = gb[b] + p;
    }
    __syncthreads();
    for (int j = t; j < CHSZ; j += 256)
        recs[desti[j]] = stage[j];
}

// ---- D: per-bucket (row, colseg) sort -> CSR + split ptr + packed edges ----
// seg = (col >= NN/2): layer-2 gathers hit a 3.2MB hw slice that fits L2.
__global__ __launch_bounds__(256) void sortb_k(const uint2* __restrict__ recs,
                                               const int* __restrict__ totals,
                                               int* __restrict__ rptr,
                                               int* __restrict__ rsplit,
                                               uint2* __restrict__ epack) {
    __shared__ int hist[NKEY], cur[NKEY], sc[256], ss[256];
    __shared__ int s0sh, s1sh;
    int b = blockIdx.x, t = threadIdx.x;
    int tv = (t < NB) ? totals[t] : 0;
    ss[t] = tv; __syncthreads();
    for (int off = 1; off < 256; off <<= 1) {
        int u = (t >= off) ? ss[t - off] : 0;
        __syncthreads();
        ss[t] += u;
        __syncthreads();
    }
    if (t == b) { s0sh = ss[t] - tv; s1sh = ss[t]; }
    for (int j = t; j < NKEY; j += 256) hist[j] = 0;
    __syncthreads();
    int s0 = s0sh, s1 = s1sh;
    for (int i = s0 + t; i < s1; i += 256) {
        unsigned rx = recs[i].x;
        int col = (int)(rx & 0x1FFFF);
        int key = (int)(((rx >> 17) & 511) << 1) | (col >= (NN / 2) ? 1 : 0);
        atomicAdd(&hist[key], 1);
    }
    __syncthreads();
    int loc[4]; int lsum = 0;
#pragma unroll
    for (int j = 0; j < 4; ++j) { loc[j] = hist[t * 4 + j]; lsum += loc[j]; }
    sc[t] = lsum; __syncthreads();
    for (int off = 1; off < 256; off <<= 1) {
        int u = (t >= off) ? sc[t - off] : 0;
        __syncthreads();
        sc[t] += u;
        __syncthreads();
    }
    int run = sc[t] - lsum;
#pragma unroll
    for (int j = 0; j < 4; ++j) { cur[t * 4 + j] = run; run += loc[j]; }
    __syncthreads();
    int nrows = NN - b * 512; if (nrows > 512) nrows = 512;
    for (int j = t; j < nrows; j += 256) {
        rptr[b * 512 + j]   = s0 + cur[j * 2];
        rsplit[b * 512 + j] = s0 + cur[j * 2 + 1];
    }
    if (b == 0 && t == 0) rptr[NN] = NE;
    __syncthreads();
    for (int i = s0 + t; i < s1; i += 256) {
        uint2 rc = recs[i];
        int col = (int)(rc.x & 0x1FFFF);
        int key = (int)(((rc.x >> 17) & 511) << 1) | (col >= (NN / 2) ? 1 : 0);
        int p = s0 + atomicAdd(&cur[key], 1);
        uint2 e2;
        e2.x = (unsigned)col;
        e2.y = rc.y;
        epack[p] = e2;
    }
}

#define MAC8(g, v) do { \
    acc[0] += (v) * bflo(g.x); acc[1] += (v) * bfhi(g.x); \
    acc[2] += (v) * bflo(g.y); acc[3] += (v) * bfhi(g.y); \
    acc[4] += (v) * bflo(g.z); acc[5] += (v) * bfhi(g.z); \
    acc[6] += (v) * bflo(g.w); acc[7] += (v) * bfhi(g.w); } while (0)

// ---- SpMM1: 16 lanes/edge, 4 slots, 2-deep unroll ----
__global__ __launch_bounds__(256) void spmm1_k(const int* __restrict__ rptr,
                                               const uint2* __restrict__ ep,
                                               const short* __restrict__ xb,
                                               short* __restrict__ agg1) {
    int row = blockIdx.x * 4 + (threadIdx.x >> 6);
    if (row >= NN) return;
    int lane = threadIdx.x & 63;
    int q = lane >> 4, f = lane & 15;     // edge slot / feature group (8 feats)
    int s = rptr[row], e = rptr[row + 1];
    float acc[8] = {};
    int i = s + q;
    for (; i + 4 < e; i += 8) {
        uint2 m0 = ep[i];
        uint2 m1 = ep[i + 4];
        uint4 g0 = *(const uint4*)&xb[(size_t)m0.x * NF + f * 8];
        uint4 g1 = *(const uint4*)&xb[(size_t)m1.x * NF + f * 8];
        float v0 = __uint_as_float(m0.y);
        float v1 = __uint_as_float(m1.y);
        MAC8(g0, v0); MAC8(g1, v1);
    }
    if (i < e) {
        uint2 m = ep[i];
        uint4 g = *(const uint4*)&xb[(size_t)m.x * NF + f * 8];
        float v = __uint_as_float(m.y);
        MAC8(g, v);
    }
#pragma unroll
    for (int j = 0; j < 8; ++j) {
        acc[j] += __shfl_xor(acc[j], 16, 64);
        acc[j] += __shfl_xor(acc[j], 32, 64);
    }
    if (q == 0) {
        uint4 o4;
        o4.x = ((unsigned)f2bu(acc[1]) << 16) | f2bu(acc[0]);
        o4.y = ((unsigned)f2bu(acc[3]) << 16) | f2bu(acc[2]);
        o4.z = ((unsigned)f2bu(acc[5]) << 16) | f2bu(acc[4]);
        o4.w = ((unsigned)f2bu(acc[7]) << 16) | f2bu(acc[6]);
        *(uint4*)&agg1[(size_t)row * NF + f * 8] = o4;
    }
}

// ---- fused GEMM1+HW, col-tiled: 52.2 KB LDS -> 3 blocks/CU ----
__global__ __launch_bounds__(256) void gemm12_k(const short* __restrict__ agg1,
                                                const short* __restrict__ w1t,
                                                const float* __restrict__ b1,
                                                const short* __restrict__ w2t,
                                                short* __restrict__ hw) {
    __shared__ char lds[52224];
    short* a_s  = (short*)lds;              // phase1: 64*136 = 17408 B
    short* wt_s = (short*)(lds + 17408);    // phase1: 128*136 = 34816 B
    short* h_s  = (short*)lds;              // phase2: 64*264 = 33792 B (overlay)
    short* w2_s = (short*)(lds + 33792);    // phase2: 32*264 = 16896 B
    int tid = threadIdx.x;
    int r0 = blockIdx.x * 64;
    int w = tid >> 6, l = tid & 63, lr = l & 15, hi = l >> 4;
    {   // stage A: 64 x 128
        int row = tid >> 2, kk = (tid & 3) * 32, gr = r0 + row;
        for (int i = 0; i < 4; ++i) {
            int k = kk + i * 8;
            s16x8 v = {};
            if (gr < NN) v = *(const s16x8*)&agg1[(size_t)gr * NF + k];
            *(s16x8*)&a_s[row * 136 + k] = v;
        }
    }
    f32x4 acc[2][4][2] = {};
    for (int pass = 0; pass < 2; ++pass) {
        if (pass) __syncthreads();          // pass0 mfma reads done before restage
        {   // stage W1^T tile: cols [pass*128, pass*128+128), 128 k
            int cl = tid >> 1, kk = (tid & 1) * 64;
            const short* src = &w1t[(size_t)(pass * 128 + cl) * NF + kk];
            for (int i = 0; i < 8; ++i)
                *(s16x8*)&wt_s[cl * 136 + kk + i * 8] = *(const s16x8*)&src[i * 8];
        }
        __syncthreads();
        for (int ks = 0; ks < 4; ++ks) {
            int kb = ks * 32 + hi * 8;
            s16x8 ar[4], br[2];
            for (int mi = 0; mi < 4; ++mi) ar[mi] = *(const s16x8*)&a_s[(mi * 16 + lr) * 136 + kb];
            for (int nj = 0; nj < 2; ++nj) br[nj] = *(const s16x8*)&wt_s[(w * 32 + nj * 16 + lr) * 136 + kb];
            for (int mi = 0; mi < 4; ++mi)
                for (int nj = 0; nj < 2; ++nj)
                    acc[pass][mi][nj] = __builtin_amdgcn_mfma_f32_16x16x32_bf16(ar[mi], br[nj], acc[pass][mi][nj], 0, 0, 0);
        }
    }
    float bias[2][2];
    for (int pass = 0; pass < 2; ++pass)
        for (int nj = 0; nj < 2; ++nj)
            bias[pass][nj] = b1[pass * 128 + w * 32 + nj * 16 + lr];
    __syncthreads();   // all phase-1 LDS reads complete before overlay writes
    for (int pass = 0; pass < 2; ++pass)
        for (int mi = 0; mi < 4; ++mi) {
            int rr = mi * 16 + hi * 4;
            for (int nj = 0; nj < 2; ++nj) {
                int cc = pass * 128 + w * 32 + nj * 16 + lr;
                for (int q = 0; q < 4; ++q) {
                    float v = acc[pass][mi][nj][q] + bias[pass][nj];
                    v = v > 0.f ? v : 0.f;
                    h_s[(rr + q) * 264 + cc] = (short)f2bu(v);
                }
            }
        }
    {   // stage W2^T: 32 x 256
        int c = tid >> 3, kk = (tid & 7) * 32;
        for (int i = 0; i < 4; ++i) {
            int k = kk + i * 8;
            *(s16x8*)&w2_s[c * 264 + k] = *(const s16x8*)&w2t[(size_t)c * NH1 + k];
        }
    }
    __syncthreads();
    f32x4 acc2[2] = {};
    for (int ks = 0; ks < 8; ++ks) {
        int kb = ks * 32 + hi * 8;
        s16x8 ar = *(const s16x8*)&h_s[(w * 16 + lr) * 264 + kb];
        for (int nj = 0; nj < 2; ++nj) {
            s16x8 br = *(const s16x8*)&w2_s[(nj * 16 + lr) * 264 + kb];
            acc2[nj] = __builtin_amdgcn_mfma_f32_16x16x32_bf16(ar, br, acc2[nj], 0, 0, 0);
        }
    }
    for (int nj = 0; nj < 2; ++nj) {
        int c = nj * 16 + lr;
        for (int q = 0; q < 4; ++q) {
            int r = r0 + w * 16 + hi * 4 + q;
            if (r < NN) hw[(size_t)r * NH2 + c] = (short)f2bu(acc2[nj][q]);
        }
    }
}

#define MAC4(g, v) do { \
    a0 += (v) * bflo(g.x); a1 += (v) * bfhi(g.x); \
    a2 += (v) * bflo(g.y); a3 += (v) * bfhi(g.y); } while (0)

// ---- SpMM2 pass A: cols < NN/2 (3.2MB hw slice, L2-resident). f32 partials ----
__global__ __launch_bounds__(256) void spmm2a_k(const int* __restrict__ rptr,
                                                const int* __restrict__ rsplit,
                                                const uint2* __restrict__ ep,
                                                const short* __restrict__ hw,
                                                float* __restrict__ tpart) {
    int row = blockIdx.x * 4 + (threadIdx.x >> 6);
    int lane = threadIdx.x & 63;
    int o = lane >> 3, f = lane & 7;      // edge slot / feature group (4 feats)
    int s = rptr[row], e = rsplit[row];
    float a0 = 0.f, a1 = 0.f, a2 = 0.f, a3 = 0.f;
    int i = s + o;
    for (; i + 8 < e; i += 16) {
        uint2 m0 = ep[i], m1 = ep[i + 8];
        uint2 g0 = *(const uint2*)&hw[(size_t)m0.x * NH2 + f * 4];
        uint2 g1 = *(const uint2*)&hw[(size_t)m1.x * NH2 + f * 4];
        float v0 = __uint_as_float(m0.y), v1 = __uint_as_float(m1.y);
        MAC4(g0, v0); MAC4(g1, v1);
    }
    if (i < e) {
        uint2 m = ep[i];
        uint2 g = *(const uint2*)&hw[(size_t)m.x * NH2 + f * 4];
        float v = __uint_as_float(m.y);
        MAC4(g, v);
    }
    a0 += __shfl_xor(a0, 8, 64); a0 += __shfl_xor(a0, 16, 64); a0 += __shfl_xor(a0, 32, 64);
    a1 += __shfl_xor(a1, 8, 64); a1 += __shfl_xor(a1, 16, 64); a1 += __shfl_xor(a1, 32, 64);
    a2 += __shfl_xor(a2, 8, 64); a2 += __shfl_xor(a2, 16, 64); a2 += __shfl_xor(a2, 32, 64);
    a3 += __shfl_xor(a3, 8, 64); a3 += __shfl_xor(a3, 16, 64); a3 += __shfl_xor(a3, 32, 64);
    if (o == 0) {
        f32x4 ov; ov[0] = a0; ov[1] = a1; ov[2] = a2; ov[3] = a3;
        __builtin_nontemporal_store(ov, (f32x4*)&tpart[(size_t)row * NH2 + f * 4]);
    }
}

// ---- SpMM2 pass B: cols >= NN/2 + partial + bias + relu -> t ----
__global__ __launch_bounds__(256) void spmm2b_k(const int* __restrict__ rptr,
                                                const int* __restrict__ rsplit,
                                                const uint2* __restrict__ ep,
                                                const short* __restrict__ hw,
                                                const float* __restrict__ tpart,
                                                const float* __restrict__ b2,
                                                float* __restrict__ t_out) {
    int row = blockIdx.x * 4 + (threadIdx.x >> 6);
    int lane = threadIdx.x & 63;
    int o = lane >> 3, f = lane & 7;
    int s = rsplit[row], e = rptr[row + 1];
    float a0 = 0.f, a1 = 0.f, a2 = 0.f, a3 = 0.f;
    int i = s + o;
    for (; i + 8 < e; i += 16) {
        uint2 m0 = ep[i], m1 = ep[i + 8];
        uint2 g0 = *(const uint2*)&hw[(size_t)m0.x * NH2 + f * 4];
        uint2 g1 = *(const uint2*)&hw[(size_t)m1.x * NH2 + f * 4];
        float v0 = __uint_as_float(m0.y), v1 = __uint_as_float(m1.y);
        MAC4(g0, v0); MAC4(g1, v1);
    }
    if (i < e) {
        uint2 m = ep[i];
        uint2 g = *(const uint2*)&hw[(size_t)m.x * NH2 + f * 4];
        float v = __uint_as_float(m.y);
        MAC4(g, v);
    }
    a0 += __shfl_xor(a0, 8, 64); a0 += __shfl_xor(a0, 16, 64); a0 += __shfl_xor(a0, 32, 64);
    a1 += __shfl_xor(a1, 8, 64); a1 += __shfl_xor(a1, 16, 64); a1 += __shfl_xor(a1, 32, 64);
    a2 += __shfl_xor(a2, 8, 64); a2 += __shfl_xor(a2, 16, 64); a2 += __shfl_xor(a2, 32, 64);
    a3 += __shfl_xor(a3, 8, 64); a3 += __shfl_xor(a3, 16, 64); a3 += __shfl_xor(a3, 32, 64);
    if (o == 0) {
        f32x4 pv = __builtin_nontemporal_load((const f32x4*)&tpart[(size_t)row * NH2 + f * 4]);
        float r0 = a0 + pv[0] + b2[f * 4];
        float r1 = a1 + pv[1] + b2[f * 4 + 1];
        float r2 = a2 + pv[2] + b2[f * 4 + 2];
        float r3 = a3 + pv[3] + b2[f * 4 + 3];
        f32x4 ov;
        ov[0] = r0 > 0.f ? r0 : 0.f;
        ov[1] = r1 > 0.f ? r1 : 0.f;
        ov[2] = r2 > 0.f ? r2 : 0.f;
        ov[3] = r3 > 0.f ? r3 : 0.f;
        *(f32x4*)&t_out[(size_t)row * NH2 + f * 4] = ov;
    }
}

// ---- GEMM3 + log_softmax ----
__global__ __launch_bounds__(256) void gemm3_k(const float* __restrict__ t_in,
                                               const float* __restrict__ W3,
                                               const float* __restrict__ b3,
                                               float* __restrict__ out) {
    __shared__ float t_s[256 * 33];
    __shared__ float w3s[NH2 * NC];
    __shared__ float b3s[NC];
    int tid = threadIdx.x;
    int r0 = blockIdx.x * 256;
    for (int j = 0; j < 32; ++j) {
        int flat = tid + j * 256;
        int r = flat >> 5, k = flat & 31;
        int gr = r0 + r;
        t_s[r * 33 + k] = (gr < NN) ? t_in[(size_t)gr * NH2 + k] : 0.f;
    }
    for (int j = tid; j < NH2 * NC; j += 256) w3s[j] = W3[j];
    if (tid < NC) b3s[tid] = b3[tid];
    __syncthreads();
    int gr = r0 + tid;
    if (gr >= NN) return;
    float lg[NC];
    for (int c = 0; c < NC; ++c) lg[c] = b3s[c];
    for (int k = 0; k < NH2; ++k) {
        float a = t_s[tid * 33 + k];
        for (int c = 0; c < NC; ++c) lg[c] += a * w3s[k * NC + c];
    }
    float m = lg[0];
    for (int c = 1; c < NC; ++c) m = fmaxf(m, lg[c]);
    float s = 0.f;
    for (int c = 0; c < NC; ++c) s += expf(lg[c] - m);
    float lo = logf(s) + m;
    f32x4* po = (f32x4*)&out[(size_t)gr * NC];
    for (int c4 = 0; c4 < 4; ++c4) {
        f32x4 v;
        for (int q = 0; q < 4; ++q) v[q] = lg[c4 * 4 + q] - lo;
        po[c4] = v;
    }
}

extern "C" void kernel_launch(void* const* d_in, const int* in_sizes, int n_in,
                              void* d_out, int out_size, void* d_ws, size_t ws_size,
                              hipStream_t stream) {
    const float* x_in  = (const float*)d_in[0];
    const int*   arow  = (const int*)d_in[1];
    const int*   acol  = (const int*)d_in[2];
    const float* avals = (const float*)d_in[3];
    const float* W1    = (const float*)d_in[4];
    const float* b1    = (const float*)d_in[5];
    const float* W2    = (const float*)d_in[6];
    const float* b2    = (const float*)d_in[7];
    const float* W3    = (const float*)d_in[8];
    const float* b3    = (const float*)d_in[9];
    float* out = (float*)d_out;
    float* t_out = out + (size_t)NN * NC;

    char* p = (char*)d_ws;
    size_t o = 0;
    auto alloc = [&](size_t bytes) -> void* {
        void* r = p + o;
        o += (bytes + 255) & ~(size_t)255;
        return r;
    };
    uint2* recs  = (uint2*)alloc((size_t)NE * 8);
    uint2* epack = (uint2*)alloc((size_t)NE * 8);
    int*   histc = (int*)  alloc((size_t)NCHUNK * NB * 4);
    int*   cur   = (int*)  alloc((size_t)NCHUNK * NB * 4);
    int*   totals= (int*)  alloc((size_t)NB * 4);
    int*   rptr  = (int*)  alloc((size_t)(NN + 1) * 4);
    int*   rsplit= (int*)  alloc((size_t)NN * 4);
    short* w1t   = (short*)alloc((size_t)NF * NH1 * 2);
    short* w2t   = (short*)alloc((size_t)NH1 * NH2 * 2);
    short* xb    = (short*)alloc((size_t)NN * NF * 2);
    short* agg1  = (short*)alloc((size_t)NN * NF * 2);
    short* hw    = (short*)alloc((size_t)NN * NH2 * 2);
    float* tpart = (float*)alloc((size_t)NN * NH2 * 4);

    fat0_k<<<NCHUNK + 1024 + 160, 256, 0, stream>>>(x_in, xb, W1, W2, w1t, w2t, arow, histc);
    scanb_k<<<NB, 256, 0, stream>>>(histc, cur, totals);
    scat_k<<<NCHUNK, 256, 0, stream>>>(arow, acol, avals, totals, histc, cur, recs);
    sortb_k<<<NB, 256, 0, stream>>>(recs, totals, rptr, rsplit, epack);
    spmm1_k<<<25000, 256, 0, stream>>>(rptr, epack, xb, agg1);
    gemm12_k<<<1563, 256, 0, stream>>>(agg1, w1t, b1, w2t, hw);
    spmm2a_k<<<25000, 256, 0, stream>>>(rptr, rsplit, epack, hw, tpart);
    spmm2b_k<<<25000, 256, 0, stream>>>(rptr, rsplit, epack, hw, tpart, b2, t_out);
    gemm3_k<<<391, 256, 0, stream>>>(t_out, W3, b3, out);
}

// Round 12
// 197.923 us; speedup vs baseline: 1.1698x; 1.1698x over previous
//
#include <hip/hip_runtime.h>
#include <hip/hip_bf16.h>

#define NN 100000
#define NE 1600000
#define NF 128
#define NH1 256
#define NH2 32
#define NC 16

#define NB 196          // row buckets (512 rows each)
#define BSH 9
#define NCHUNK 512
#define CHSZ (NE / NCHUNK)   // 3125

typedef __attribute__((ext_vector_type(4))) float f32x4;
typedef __attribute__((ext_vector_type(8))) short s16x8;
typedef __attribute__((ext_vector_type(4))) short s16x4;

__device__ __forceinline__ unsigned short f2bu(float f) {
    union { float f; unsigned u; } v; v.f = f;
    unsigned r = v.u + 0x7FFFu + ((v.u >> 16) & 1u);
    return (unsigned short)(r >> 16);
}
__device__ __forceinline__ float bflo(unsigned w) { return __uint_as_float(w << 16); }
__device__ __forceinline__ float bfhi(unsigned w) { return __uint_as_float(w & 0xFFFF0000u); }

// int64-vs-int32 probe, inlined per consuming block (16 uniform loads)
__device__ __forceinline__ int detect_st(const int* arow) {
    const unsigned* a = (const unsigned*)arow;
    unsigned acc = 0;
#pragma unroll
    for (int i = 1; i < 32; i += 2) acc |= a[i];
    return acc == 0u ? 2 : 1;
}

// ---- fat0: hist (blocks 0..511) | xconv (512..1535) | prep (1536..1695) ----
__global__ __launch_bounds__(256) void fat0_k(const float* __restrict__ x, short* __restrict__ xb,
                                              const float* __restrict__ W1, const float* __restrict__ W2,
                                              short* __restrict__ w1t, short* __restrict__ w2t,
                                              const int* __restrict__ arow, int* __restrict__ histc) {
    int bid = blockIdx.x;
    if (bid < NCHUNK) {                       // per-chunk bucket histogram
        __shared__ int h[NB];
        for (int j = threadIdx.x; j < NB; j += 256) h[j] = 0;
        __syncthreads();
        int st = detect_st(arow);
        int base = bid * CHSZ;
        for (int i = base + threadIdx.x; i < base + CHSZ; i += 256)
            atomicAdd(&h[arow[(size_t)i * st] >> BSH], 1);
        __syncthreads();
        for (int j = threadIdx.x; j < NB; j += 256) histc[bid * NB + j] = h[j];
    } else if (bid < NCHUNK + 1024) {         // x -> bf16
        const int total = NN * NF / 4;
        for (int i = (bid - NCHUNK) * 256 + threadIdx.x; i < total; i += 1024 * 256) {
            f32x4 v = ((const f32x4*)x)[i];
            s16x4 o;
            for (int j = 0; j < 4; ++j) o[j] = (short)f2bu(v[j]);
            ((s16x4*)xb)[i] = o;
        }
    } else {                                  // weight transpose + bf16
        int i = (bid - NCHUNK - 1024) * 256 + threadIdx.x;
        if (i < NF * NH1) {
            int k = i / NH1, c = i % NH1;
            w1t[c * NF + k] = (short)f2bu(W1[i]);
        } else {
            int j = i - NF * NH1;
            if (j < NH1 * NH2) {
                int k = j / NH2, c = j % NH2;
                w2t[c * NH1 + k] = (short)f2bu(W2[j]);
            }
        }
    }
}

// ---- B1: per-bucket exclusive scan over chunks ----
__global__ __launch_bounds__(256) void scanb_k(const int* __restrict__ histc,
                                               int* __restrict__ cur,
                                               int* __restrict__ totals) {
    __shared__ int s[256];
    int b = blockIdx.x, t = threadIdx.x;
    int v0 = histc[(2 * t) * NB + b], v1 = histc[(2 * t + 1) * NB + b];
    int sum = v0 + v1;
    s[t] = sum; __syncthreads();
    for (int off = 1; off < 256; off <<= 1) {
        int u = (t >= off) ? s[t - off] : 0;
        __syncthreads();
        s[t] += u;
        __syncthreads();
    }
    int excl = s[t] - sum;
    cur[(2 * t) * NB + b] = excl;
    cur[(2 * t + 1) * NB + b] = excl + v0;
    if (t == 255) totals[b] = s[255];
}

// ---- C: scatter via LDS staging -> run-coalesced global writes ----
__global__ __launch_bounds__(256) void scat_k(const int* __restrict__ arow,
                                              const int* __restrict__ acol,
                                              const float* __restrict__ avals,
                                              const int* __restrict__ totals,
                                              const int* __restrict__ histc,
                                              const int* __restrict__ cur,
                                              uint2* __restrict__ recs) {
    __shared__ uint2 stage[CHSZ];     // 25000 B
    __shared__ int desti[CHSZ];       // 12500 B
    __shared__ int gb[NB];            // gbase[b] - binoff[b]
    __shared__ int bincur[NB];
    __shared__ int ss[256];
    int c = blockIdx.x, t = threadIdx.x;
    int tv = (t < NB) ? totals[t] : 0;
    ss[t] = tv; __syncthreads();
    for (int off = 1; off < 256; off <<= 1) {
        int u = (t >= off) ? ss[t - off] : 0;
        __syncthreads();
        ss[t] += u;
        __syncthreads();
    }
    int bstart = ss[t] - tv;
    if (t < NB) gb[t] = bstart + cur[c * NB + t];
    __syncthreads();
    int hv = (t < NB) ? histc[c * NB + t] : 0;
    ss[t] = hv; __syncthreads();
    for (int off = 1; off < 256; off <<= 1) {
        int u = (t >= off) ? ss[t - off] : 0;
        __syncthreads();
        ss[t] += u;
        __syncthreads();
    }
    int boff = ss[t] - hv;
    if (t < NB) { bincur[t] = boff; gb[t] -= boff; }
    __syncthreads();
    int st = detect_st(arow);
    int base = c * CHSZ;
    for (int i = base + t; i < base + CHSZ; i += 256) {
        int r   = arow[(size_t)i * st];
        int col = acol[(size_t)i * st];
        float v = avals[i];
        int b = r >> BSH;
        int p = atomicAdd(&bincur[b], 1);
        uint2 rec;
        rec.x = (unsigned)col | ((unsigned)(r & 511) << 17);
        rec.y = __float_as_uint(v);
        stage[p] = rec;
        desti[p] = gb[b] + p;
    }
    __syncthreads();
    for (int j = t; j < CHSZ; j += 256)
        recs[desti[j]] = stage[j];
}

// ---- D: per-bucket row sort -> CSR + packed (col,val) edge array ----
__global__ __launch_bounds__(256) void sortb_k(const uint2* __restrict__ recs,
                                               const int* __restrict__ totals,
                                               int* __restrict__ rptr,
                                               uint2* __restrict__ epack) {
    __shared__ int hist[512], cur[512], sc[256], ss[256];
    __shared__ int s0sh, s1sh;
    int b = blockIdx.x, t = threadIdx.x;
    int tv = (t < NB) ? totals[t] : 0;
    ss[t] = tv; __syncthreads();
    for (int off = 1; off < 256; off <<= 1) {
        int u = (t >= off) ? ss[t - off] : 0;
        __syncthreads();
        ss[t] += u;
        __syncthreads();
    }
    if (t == b) { s0sh = ss[t] - tv; s1sh = ss[t]; }
    for (int j = t; j < 512; j += 256) hist[j] = 0;
    __syncthreads();
    int s0 = s0sh, s1 = s1sh;
    for (int i = s0 + t; i < s1; i += 256)
        atomicAdd(&hist[(recs[i].x >> 17) & 511], 1);
    __syncthreads();
    int v0 = hist[2 * t], v1 = hist[2 * t + 1], sum = v0 + v1;
    sc[t] = sum; __syncthreads();
    for (int off = 1; off < 256; off <<= 1) {
        int u = (t >= off) ? sc[t - off] : 0;
        __syncthreads();
        sc[t] += u;
        __syncthreads();
    }
    int excl = sc[t] - sum;
    cur[2 * t] = excl; cur[2 * t + 1] = excl + v0;
    __syncthreads();
    int nrows = NN - b * 512; if (nrows > 512) nrows = 512;
    for (int j = t; j < nrows; j += 256) rptr[b * 512 + j] = s0 + cur[j];
    if (b == 0 && t == 0) rptr[NN] = NE;
    __syncthreads();
    for (int i = s0 + t; i < s1; i += 256) {
        uint2 rc = recs[i];
        int rl = (rc.x >> 17) & 511;
        int p = s0 + atomicAdd(&cur[rl], 1);
        uint2 ep;
        ep.x = rc.x & 0x1FFFF;
        ep.y = rc.y;
        epack[p] = ep;
    }
}

#define MAC8(g, v) do { \
    acc[0] += (v) * bflo(g.x); acc[1] += (v) * bfhi(g.x); \
    acc[2] += (v) * bflo(g.y); acc[3] += (v) * bfhi(g.y); \
    acc[4] += (v) * bflo(g.z); acc[5] += (v) * bfhi(g.z); \
    acc[6] += (v) * bflo(g.w); acc[7] += (v) * bfhi(g.w); } while (0)

// ---- SpMM1: 16 lanes/edge, 4 slots, 2-deep unroll ----
__global__ __launch_bounds__(256) void spmm1_k(const int* __restrict__ rptr,
                                               const uint2* __restrict__ ep,
                                               const short* __restrict__ xb,
                                               short* __restrict__ agg1) {
    int row = blockIdx.x * 4 + (threadIdx.x >> 6);
    if (row >= NN) return;
    int lane = threadIdx.x & 63;
    int q = lane >> 4, f = lane & 15;     // edge slot / feature group (8 feats)
    int s = rptr[row], e = rptr[row + 1];
    float acc[8] = {};
    int i = s + q;
    for (; i + 4 < e; i += 8) {
        uint2 m0 = ep[i];
        uint2 m1 = ep[i + 4];
        uint4 g0 = *(const uint4*)&xb[(size_t)m0.x * NF + f * 8];
        uint4 g1 = *(const uint4*)&xb[(size_t)m1.x * NF + f * 8];
        float v0 = __uint_as_float(m0.y);
        float v1 = __uint_as_float(m1.y);
        MAC8(g0, v0); MAC8(g1, v1);
    }
    if (i < e) {
        uint2 m = ep[i];
        uint4 g = *(const uint4*)&xb[(size_t)m.x * NF + f * 8];
        float v = __uint_as_float(m.y);
        MAC8(g, v);
    }
#pragma unroll
    for (int j = 0; j < 8; ++j) {
        acc[j] += __shfl_xor(acc[j], 16, 64);
        acc[j] += __shfl_xor(acc[j], 32, 64);
    }
    if (q == 0) {
        uint4 o4;
        o4.x = ((unsigned)f2bu(acc[1]) << 16) | f2bu(acc[0]);
        o4.y = ((unsigned)f2bu(acc[3]) << 16) | f2bu(acc[2]);
        o4.z = ((unsigned)f2bu(acc[5]) << 16) | f2bu(acc[4]);
        o4.w = ((unsigned)f2bu(acc[7]) << 16) | f2bu(acc[6]);
        *(uint4*)&agg1[(size_t)row * NF + f * 8] = o4;
    }
}

// ---- fused GEMM1+HW, col-tiled; epilogue: int8 per-row quant of hw ----
__global__ __launch_bounds__(256) void gemm12_k(const short* __restrict__ agg1,
                                                const short* __restrict__ w1t,
                                                const float* __restrict__ b1,
                                                const short* __restrict__ w2t,
                                                signed char* __restrict__ hw8,
                                                float* __restrict__ srow) {
    __shared__ char lds[52224];
    short* a_s  = (short*)lds;              // phase1: 64*136 = 17408 B
    short* wt_s = (short*)(lds + 17408);    // phase1: 128*136 = 34816 B
    short* h_s  = (short*)lds;              // phase2: 64*264 = 33792 B (overlay)
    short* w2_s = (short*)(lds + 33792);    // phase2: 32*264 = 16896 B
    int tid = threadIdx.x;
    int r0 = blockIdx.x * 64;
    int w = tid >> 6, l = tid & 63, lr = l & 15, hi = l >> 4;
    {   // stage A: 64 x 128
        int row = tid >> 2, kk = (tid & 3) * 32, gr = r0 + row;
        for (int i = 0; i < 4; ++i) {
            int k = kk + i * 8;
            s16x8 v = {};
            if (gr < NN) v = *(const s16x8*)&agg1[(size_t)gr * NF + k];
            *(s16x8*)&a_s[row * 136 + k] = v;
        }
    }
    f32x4 acc[2][4][2] = {};
    for (int pass = 0; pass < 2; ++pass) {
        if (pass) __syncthreads();          // pass0 mfma reads done before restage
        {   // stage W1^T tile: cols [pass*128, pass*128+128), 128 k
            int cl = tid >> 1, kk = (tid & 1) * 64;
            const short* src = &w1t[(size_t)(pass * 128 + cl) * NF + kk];
            for (int i = 0; i < 8; ++i)
                *(s16x8*)&wt_s[cl * 136 + kk + i * 8] = *(const s16x8*)&src[i * 8];
        }
        __syncthreads();
        for (int ks = 0; ks < 4; ++ks) {
            int kb = ks * 32 + hi * 8;
            s16x8 ar[4], br[2];
            for (int mi = 0; mi < 4; ++mi) ar[mi] = *(const s16x8*)&a_s[(mi * 16 + lr) * 136 + kb];
            for (int nj = 0; nj < 2; ++nj) br[nj] = *(const s16x8*)&wt_s[(w * 32 + nj * 16 + lr) * 136 + kb];
            for (int mi = 0; mi < 4; ++mi)
                for (int nj = 0; nj < 2; ++nj)
                    acc[pass][mi][nj] = __builtin_amdgcn_mfma_f32_16x16x32_bf16(ar[mi], br[nj], acc[pass][mi][nj], 0, 0, 0);
        }
    }
    float bias[2][2];
    for (int pass = 0; pass < 2; ++pass)
        for (int nj = 0; nj < 2; ++nj)
            bias[pass][nj] = b1[pass * 128 + w * 32 + nj * 16 + lr];
    __syncthreads();   // all phase-1 LDS reads complete before overlay writes
    for (int pass = 0; pass < 2; ++pass)
        for (int mi = 0; mi < 4; ++mi) {
            int rr = mi * 16 + hi * 4;
            for (int nj = 0; nj < 2; ++nj) {
                int cc = pass * 128 + w * 32 + nj * 16 + lr;
                for (int q = 0; q < 4; ++q) {
                    float v = acc[pass][mi][nj][q] + bias[pass][nj];
                    v = v > 0.f ? v : 0.f;
                    h_s[(rr + q) * 264 + cc] = (short)f2bu(v);
                }
            }
        }
    {   // stage W2^T: 32 x 256
        int c = tid >> 3, kk = (tid & 7) * 32;
        for (int i = 0; i < 4; ++i) {
            int k = kk + i * 8;
            *(s16x8*)&w2_s[c * 264 + k] = *(const s16x8*)&w2t[(size_t)c * NH1 + k];
        }
    }
    __syncthreads();
    f32x4 acc2[2] = {};
    for (int ks = 0; ks < 8; ++ks) {
        int kb = ks * 32 + hi * 8;
        s16x8 ar = *(const s16x8*)&h_s[(w * 16 + lr) * 264 + kb];
        for (int nj = 0; nj < 2; ++nj) {
            s16x8 br = *(const s16x8*)&w2_s[(nj * 16 + lr) * 264 + kb];
            acc2[nj] = __builtin_amdgcn_mfma_f32_16x16x32_bf16(ar, br, acc2[nj], 0, 0, 0);
        }
    }
    // epilogue: per-row max over the 32 cols (lanes lr x nj), quantize to int8
    for (int q = 0; q < 4; ++q) {
        float m = fmaxf(fabsf(acc2[0][q]), fabsf(acc2[1][q]));
        m = fmaxf(m, __shfl_xor(m, 1, 64));
        m = fmaxf(m, __shfl_xor(m, 2, 64));
        m = fmaxf(m, __shfl_xor(m, 4, 64));
        m = fmaxf(m, __shfl_xor(m, 8, 64));
        float sc = fmaxf(m * (1.f / 127.f), 1e-30f);
        int r = r0 + w * 16 + hi * 4 + q;
        if (r < NN) {
            if (lr == 0) srow[r] = sc;
            float inv = 1.f / sc;
            hw8[(size_t)r * NH2 + lr]      = (signed char)__float2int_rn(acc2[0][q] * inv);
            hw8[(size_t)r * NH2 + 16 + lr] = (signed char)__float2int_rn(acc2[1][q] * inv);
        }
    }
}

// ---- SpMM2: int8 gather (3.6MB working set, L2-resident) + bias + relu ----
__global__ __launch_bounds__(256) void spmm2_k(const int* __restrict__ rptr,
                                               const uint2* __restrict__ ep,
                                               const signed char* __restrict__ hw8,
                                               const float* __restrict__ srow,
                                               const float* __restrict__ b2,
                                               float* __restrict__ t_out) {
    int row = blockIdx.x * 4 + (threadIdx.x >> 6);
    if (row >= NN) return;
    int lane = threadIdx.x & 63;
    int o = lane >> 3, f = lane & 7;      // edge slot / feature group (4 feats)
    int s = rptr[row], e = rptr[row + 1];
    float a0 = 0.f, a1 = 0.f, a2 = 0.f, a3 = 0.f;
    int i = s + o;
    for (; i + 8 < e; i += 16) {
        uint2 m0 = ep[i], m1 = ep[i + 8];
        unsigned p0 = *(const unsigned*)&hw8[(size_t)m0.x * NH2 + f * 4];
        unsigned p1 = *(const unsigned*)&hw8[(size_t)m1.x * NH2 + f * 4];
        float v0 = __uint_as_float(m0.y) * srow[m0.x];
        float v1 = __uint_as_float(m1.y) * srow[m1.x];
        a0 += v0 * (float)(signed char)(p0);
        a1 += v0 * (float)(signed char)(p0 >> 8);
        a2 += v0 * (float)(signed char)(p0 >> 16);
        a3 += v0 * (float)(signed char)(p0 >> 24);
        a0 += v1 * (float)(signed char)(p1);
        a1 += v1 * (float)(signed char)(p1 >> 8);
        a2 += v1 * (float)(signed char)(p1 >> 16);
        a3 += v1 * (float)(signed char)(p1 >> 24);
    }
    if (i < e) {
        uint2 m = ep[i];
        unsigned p = *(const unsigned*)&hw8[(size_t)m.x * NH2 + f * 4];
        float v = __uint_as_float(m.y) * srow[m.x];
        a0 += v * (float)(signed char)(p);
        a1 += v * (float)(signed char)(p >> 8);
        a2 += v * (float)(signed char)(p >> 16);
        a3 += v * (float)(signed char)(p >> 24);
    }
    a0 += __shfl_xor(a0, 8, 64); a0 += __shfl_xor(a0, 16, 64); a0 += __shfl_xor(a0, 32, 64);
    a1 += __shfl_xor(a1, 8, 64); a1 += __shfl_xor(a1, 16, 64); a1 += __shfl_xor(a1, 32, 64);
    a2 += __shfl_xor(a2, 8, 64); a2 += __shfl_xor(a2, 16, 64); a2 += __shfl_xor(a2, 32, 64);
    a3 += __shfl_xor(a3, 8, 64); a3 += __shfl_xor(a3, 16, 64); a3 += __shfl_xor(a3, 32, 64);
    if (o == 0) {
        float r0 = a0 + b2[f * 4];
        float r1 = a1 + b2[f * 4 + 1];
        float r2 = a2 + b2[f * 4 + 2];
        float r3 = a3 + b2[f * 4 + 3];
        f32x4 ov;
        ov[0] = r0 > 0.f ? r0 : 0.f;
        ov[1] = r1 > 0.f ? r1 : 0.f;
        ov[2] = r2 > 0.f ? r2 : 0.f;
        ov[3] = r3 > 0.f ? r3 : 0.f;
        *(f32x4*)&t_out[(size_t)row * NH2 + f * 4] = ov;
    }
}

// ---- GEMM3 + log_softmax ----
__global__ __launch_bounds__(256) void gemm3_k(const float* __restrict__ t_in,
                                               const float* __restrict__ W3,
                                               const float* __restrict__ b3,
                                               float* __restrict__ out) {
    __shared__ float t_s[256 * 33];
    __shared__ float w3s[NH2 * NC];
    __shared__ float b3s[NC];
    int tid = threadIdx.x;
    int r0 = blockIdx.x * 256;
    for (int j = 0; j < 32; ++j) {
        int flat = tid + j * 256;
        int r = flat >> 5, k = flat & 31;
        int gr = r0 + r;
        t_s[r * 33 + k] = (gr < NN) ? t_in[(size_t)gr * NH2 + k] : 0.f;
    }
    for (int j = tid; j < NH2 * NC; j += 256) w3s[j] = W3[j];
    if (tid < NC) b3s[tid] = b3[tid];
    __syncthreads();
    int gr = r0 + tid;
    if (gr >= NN) return;
    float lg[NC];
    for (int c = 0; c < NC; ++c) lg[c] = b3s[c];
    for (int k = 0; k < NH2; ++k) {
        float a = t_s[tid * 33 + k];
        for (int c = 0; c < NC; ++c) lg[c] += a * w3s[k * NC + c];
    }
    float m = lg[0];
    for (int c = 1; c < NC; ++c) m = fmaxf(m, lg[c]);
    float s = 0.f;
    for (int c = 0; c < NC; ++c) s += expf(lg[c] - m);
    float lo = logf(s) + m;
    f32x4* po = (f32x4*)&out[(size_t)gr * NC];
    for (int c4 = 0; c4 < 4; ++c4) {
        f32x4 v;
        for (int q = 0; q < 4; ++q) v[q] = lg[c4 * 4 + q] - lo;
        po[c4] = v;
    }
}

extern "C" void kernel_launch(void* const* d_in, const int* in_sizes, int n_in,
                              void* d_out, int out_size, void* d_ws, size_t ws_size,
                              hipStream_t stream) {
    const float* x_in  = (const float*)d_in[0];
    const int*   arow  = (const int*)d_in[1];
    const int*   acol  = (const int*)d_in[2];
    const float* avals = (const float*)d_in[3];
    const float* W1    = (const float*)d_in[4];
    const float* b1    = (const float*)d_in[5];
    const float* W2    = (const float*)d_in[6];
    const float* b2    = (const float*)d_in[7];
    const float* W3    = (const float*)d_in[8];
    const float* b3    = (const float*)d_in[9];
    float* out = (float*)d_out;
    float* t_out = out + (size_t)NN * NC;

    char* p = (char*)d_ws;
    size_t o = 0;
    auto alloc = [&](size_t bytes) -> void* {
        void* r = p + o;
        o += (bytes + 255) & ~(size_t)255;
        return r;
    };
    uint2* recs  = (uint2*)alloc((size_t)NE * 8);
    uint2* epack = (uint2*)alloc((size_t)NE * 8);
    int*   histc = (int*)  alloc((size_t)NCHUNK * NB * 4);
    int*   cur   = (int*)  alloc((size_t)NCHUNK * NB * 4);
    int*   totals= (int*)  alloc((size_t)NB * 4);
    int*   rptr  = (int*)  alloc((size_t)(NN + 1) * 4);
    short* w1t   = (short*)alloc((size_t)NF * NH1 * 2);
    short* w2t   = (short*)alloc((size_t)NH1 * NH2 * 2);
    short* xb    = (short*)alloc((size_t)NN * NF * 2);
    short* agg1  = (short*)alloc((size_t)NN * NF * 2);
    signed char* hw8 = (signed char*)alloc((size_t)NN * NH2);
    float* srow  = (float*)alloc((size_t)NN * 4);

    fat0_k<<<NCHUNK + 1024 + 160, 256, 0, stream>>>(x_in, xb, W1, W2, w1t, w2t, arow, histc);
    scanb_k<<<NB, 256, 0, stream>>>(histc, cur, totals);
    scat_k<<<NCHUNK, 256, 0, stream>>>(arow, acol, avals, totals, histc, cur, recs);
    sortb_k<<<NB, 256, 0, stream>>>(recs, totals, rptr, epack);
    spmm1_k<<<25000, 256, 0, stream>>>(rptr, epack, xb, agg1);
    gemm12_k<<<1563, 256, 0, stream>>>(agg1, w1t, b1, w2t, hw8, srow);
    spmm2_k<<<25000, 256, 0, stream>>>(rptr, epack, hw8, srow, b2, t_out);
    gemm3_k<<<391, 256, 0, stream>>>(t_out, W3, b3, out);
}